// Round 4
// baseline (1001.277 us; speedup 1.0000x reference)
//
#include <hip/hip_runtime.h>
#include <cstddef>

#define Bv 4
#define Nv 24
#define NTv 16
#define Tv 64
#define NP 25
#define NEGF (-1e30f)
#define GRID 192
#define NTASK 1104

// ---------------- workspace layout (floats) ----------------
#define BETAA_OFF 0         // [B][25][25][16 sym][24 head]            960000
#define BETAU_OFF 960000    // [B][25][25][64 sym]                     160000
#define RNT_OFF   1120000   // [B][2 d][24 h][16 A][16 sL][16 sR]      786432
#define T0_OFF    1906432   // [B][24 h][24 p][16 sL][16 A]            589824
#define T1_OFF    2496256   // [B][24 h][24 p][16 sR][16 A]            589824
#define T0L_OFF   3086080   // [B][24 h][16 sR][16 A]                  24576
#define T1R_OFF   3110656   // [B][24 h][16 sL][16 A]                  24576
#define D0_OFF    3135232   // [B][24 l][16 A]                         1536
#define D1_OFF    3136768   // [B][24 l][16 A]                         1536
#define SYNC_OFF  3138304   // int region: 2500 span flags + 4 prep counters
#define WS_NEED   (3138304 + 2504)

__device__ __forceinline__ float shflmax16(float v) {
  v = fmaxf(v, __shfl_xor(v, 8, 16));
  v = fmaxf(v, __shfl_xor(v, 4, 16));
  v = fmaxf(v, __shfl_xor(v, 2, 16));
  v = fmaxf(v, __shfl_xor(v, 1, 16));
  return v;
}

// online-max outer-product update: lanes 0-15 hold left vals, 16-31 right vals
__device__ __forceinline__ void upd(float a, int k, float& G, float (&U)[8]) {
  float m16 = a;
  m16 = fmaxf(m16, __shfl_xor(m16, 8, 16));
  m16 = fmaxf(m16, __shfl_xor(m16, 4, 16));
  m16 = fmaxf(m16, __shfl_xor(m16, 2, 16));
  m16 = fmaxf(m16, __shfl_xor(m16, 1, 16));
  float other = __shfl_xor(m16, 16, 32);
  float mL = (k < 16) ? m16 : other;
  float mR = (k < 16) ? other : m16;
  float sh = mL + mR;
  float Gn = fmaxf(G, sh);
  float f = __expf(G - Gn);
  float vR = __shfl(a, 16 + (k & 15), 32);
  float vb = vR - Gn;
#pragma unroll
  for (int j = 0; j < 8; ++j) {
    float vL = __shfl(a, 2 * j + (k >> 4), 32);
    U[j] = U[j] * f + __expf(vL + vb);
  }
  G = Gn;
}

__device__ __forceinline__ void edge_dot(float v0, float v1, float v2, float v3,
                                         const float* Tb, float& sh, float& S) {
  float mx = fmaxf(fmaxf(v0, v1), fmaxf(v2, v3));
  mx = fmaxf(mx, __shfl_xor(mx, 1, 64));
  mx = fmaxf(mx, __shfl_xor(mx, 2, 64));
  float dot = __expf(v0 - mx) * Tb[0] + __expf(v1 - mx) * Tb[16] +
              __expf(v2 - mx) * Tb[32] + __expf(v3 - mx) * Tb[48];
  dot += __shfl_xor(dot, 1, 64);
  dot += __shfl_xor(dot, 2, 64);
  sh = mx;
  S = dot;
}

// ================= fused persistent kernel =================
__global__ __launch_bounds__(768) void fused_kernel(
    const float* __restrict__ unary, const float* __restrict__ rule,
    const float* __restrict__ root, float* __restrict__ out,
    float* __restrict__ betaA, float* __restrict__ betau,
    float* __restrict__ RNT, float* __restrict__ T0, float* __restrict__ T1,
    float* __restrict__ T0L, float* __restrict__ T1R,
    float* __restrict__ D0, float* __restrict__ D1,
    int* __restrict__ flags, int* __restrict__ cnt) {
  __shared__ float smem[29184];  // max(prep 3*9728, width 15088)
  const int tid = threadIdx.x, bid = blockIdx.x;

  // ---------------- prep: 1536 units (b,A,h); 3 sub-units of 256 thr per block ----------------
  {
    const int sub = tid >> 8, tpl = tid & 255;
    float* lb = smem + sub * 9728;
    float* er0 = lb;            // 64*65
    float* er1 = lb + 4160;     // 64*65
    float* E = lb + 8320;       // 24*48
    float* red = lb + 9472;     // 256
    for (int base = 0; base < 1536; base += 3 * GRID) {
      const int u = base + bid * 3 + sub;
      const bool valid = u < 1536;
      const int ue = valid ? u : 0;
      const int b = ue / 384, remu = ue % 384, A = remu / 24, h = remu % 24;
      __syncthreads();  // LDS reuse across rounds
      for (int i = tpl; i < 1152; i += 256)
        E[i] = __expf(unary[(size_t)(b * Nv + i / 48) * Tv + 16 + i % 48]);
      const float* rb = rule + (size_t)((b * NTv + A) * Nv + h) * 8192;
#pragma unroll
      for (int i = 0; i < 8; ++i) {
        int lin = i * 1024 + tpl * 4;  // sL*128 + sR*2 + d
        float4 v = *(const float4*)(rb + lin);
        int sL = lin >> 7, r2 = (lin & 127) >> 1;
        er0[sL * 65 + r2] = __expf(v.x);
        er1[sL * 65 + r2] = __expf(v.y);
        er0[sL * 65 + r2 + 1] = __expf(v.z);
        er1[sL * 65 + r2 + 1] = __expf(v.w);
      }
      __syncthreads();
      if (valid) {  // RNT, A-major
        float* dst0 = RNT + (((size_t)(b * 2 + 0) * Nv + h) * NTv + A) * 256;
        float* dst1 = RNT + (((size_t)(b * 2 + 1) * Nv + h) * NTv + A) * 256;
        dst0[tpl] = er0[(tpl >> 4) * 65 + (tpl & 15)];
        dst1[tpl] = er1[(tpl >> 4) * 65 + (tpl & 15)];
      }
      for (int o = tpl; o < 384; o += 256) {  // T0 / T1
        int p = o >> 4, sL = o & 15;
        const float* Ep = E + p * 48;
        const float* r0 = er0 + sL * 65 + 16;
        float a0 = 0.f, a1 = 0.f;
#pragma unroll 8
        for (int j = 0; j < 48; ++j) a0 += Ep[j] * r0[j];
#pragma unroll 8
        for (int i = 0; i < 48; ++i) a1 += Ep[i] * er1[(16 + i) * 65 + sL];
        if (valid) {
          T0[(((size_t)(b * Nv + h) * Nv + p) * NTv + sL) * NTv + A] = a0;
          T1[(((size_t)(b * Nv + h) * Nv + p) * NTv + sL) * NTv + A] = a1;
        }
      }
      if (tpl < 16) {  // T0L
        float acc = 0.f;
        for (int i = 0; i < 48; ++i) acc += er0[(16 + i) * 65 + tpl];
        if (valid) T0L[((size_t)(b * Nv + h) * NTv + tpl) * NTv + A] = acc;
      } else if (tpl < 32) {  // T1R
        int sL = tpl - 16;
        float acc = 0.f;
        for (int j = 0; j < 48; ++j) acc += er1[sL * 65 + 16 + j];
        if (valid) T1R[((size_t)(b * Nv + h) * NTv + sL) * NTv + A] = acc;
      }
      // D0 / D1
      float acc0 = 0.f, acc1 = 0.f;
      const int hp = (h + 1 < 24) ? h + 1 : 0, hm = (h >= 1) ? h - 1 : 0;
      for (int e = tpl; e < 2304; e += 256) {
        int i = e / 48, j = e % 48;
        acc0 += E[hp * 48 + j] * er0[(16 + i) * 65 + 16 + j];
        acc1 += E[hm * 48 + i] * er1[(16 + i) * 65 + 16 + j];
      }
      red[tpl] = acc0;
      __syncthreads();
      if (tpl < 64) {
        float s = red[tpl] + red[tpl + 64] + red[tpl + 128] + red[tpl + 192];
#pragma unroll
        for (int off = 32; off; off >>= 1) s += __shfl_xor(s, off, 64);
        if (tpl == 0 && valid && h <= 22) D0[((size_t)b * Nv + h) * NTv + A] = s;
      }
      __syncthreads();
      red[tpl] = acc1;
      __syncthreads();
      if (tpl < 64) {
        float s = red[tpl] + red[tpl + 64] + red[tpl + 128] + red[tpl + 192];
#pragma unroll
        for (int off = 32; off; off >>= 1) s += __shfl_xor(s, off, 64);
        if (tpl == 0 && valid && h >= 1) D1[((size_t)b * Nv + (h - 1)) * NTv + A] = s;
      }
      __syncthreads();  // all unit stores drained before publish
      if (tpl == 0 && valid)
        __hip_atomic_fetch_add(&cnt[b], 1, __ATOMIC_RELEASE, __HIP_MEMORY_SCOPE_AGENT);
    }
  }

  // ---------------- width tasks: dataflow over span flags ----------------
  float* U0 = smem;            // 24*256
  float* U1 = smem + 6144;     // 24*256
  float* sG0 = smem + 12288;   // 24
  float* sG1 = smem + 12312;   // 24
  float* cLs = smem + 12336;   // 16*25
  float* ecRs = smem + 12736;  // 16*25
  float* eLs = smem + 13136;   // 16
  float* eeRs = smem + 13152;  // 16
  float* pM = smem + 13168;    // 2*24*16
  float* pS = smem + 13936;    // 2*24*16
  float* sTmp = smem + 14704;  // 16*24

  for (int tau = bid; tau <= NTASK; tau += GRID) {
    if (tau == NTASK) {  // final: out[b] = lse_A(betau[b,0,24,A] + root[b,A])
      if (tid < Bv) {
        int* fp = &flags[(tid * NP + 0) * NP + Nv];
        while (__hip_atomic_load(fp, __ATOMIC_ACQUIRE, __HIP_MEMORY_SCOPE_AGENT) != 1)
          __builtin_amdgcn_s_sleep(2);
        float vals[NTv];
        float mx = NEGF;
#pragma unroll
        for (int A = 0; A < NTv; ++A) {
          float v = betau[((size_t)(tid * NP + 0) * NP + Nv) * Tv + A] + root[tid * NTv + A];
          vals[A] = v;
          mx = fmaxf(mx, v);
        }
        float s = 0.f;
#pragma unroll
        for (int A = 0; A < NTv; ++A) s += __expf(vals[A] - mx);
        out[tid] = mx + __logf(s);
      }
      continue;
    }
    // decode tau -> (W, l, b); tasks ordered by ascending W
    int remt = tau, W = 2;
    while (remt >= 4 * (25 - W)) { remt -= 4 * (25 - W); ++W; }
    const int l = remt >> 2, b = remt & 3;
    const int r = l + W;
    // ---- dependency wait ----
    if (W == 2) {
      if (tid == 0)
        while (__hip_atomic_load(&cnt[b], __ATOMIC_ACQUIRE, __HIP_MEMORY_SCOPE_AGENT) < 384)
          __builtin_amdgcn_s_sleep(2);
    } else if (tid < 2 * W - 4) {
      const int m = (tid < W - 2) ? (l + 2 + tid) : (l + 1 + (tid - (W - 2)));
      const int fi = (tid < W - 2) ? ((b * NP + l) * NP + m) : ((b * NP + m) * NP + r);
      while (__hip_atomic_load(&flags[fi], __ATOMIC_ACQUIRE, __HIP_MEMORY_SCOPE_AGENT) != 1)
        __builtin_amdgcn_s_sleep(2);
    }
    __syncthreads();

    // ---- edge staging ----
    if (W >= 3) {
      if (tid < 384) {
        int s = tid / 24, j = tid % 24, jj = j - l;
        float v = betaA[((size_t)(b * NP + l) * NP + (r - 1)) * 384 + s * 24 + j];
        if (jj >= 0 && jj < 24) cLs[s * 25 + jj] = v;
      } else {
        int t2 = tid - 384;
        int s = t2 / 24, j = t2 % 24, jj = j - l;
        float v = betaA[((size_t)(b * NP + (l + 1)) * NP + r) * 384 + s * 24 + j];
        if (jj >= 0 && jj < 24) ecRs[s * 25 + jj] = v;
      }
      if (tid < 16) eLs[tid] = betau[((size_t)(b * NP + l) * NP + (r - 1)) * Tv + tid];
      else if (tid >= 32 && tid < 48)
        eeRs[tid - 32] = betau[((size_t)(b * NP + (l + 1)) * NP + r) * Tv + (tid - 32)];
    }

    // ---- Phase A: per-head register-U accumulation over interior splits ----
    const int g = tid >> 5;
    const int k = tid & 31;
    float U0r[8], U1r[8];
#pragma unroll
    for (int j = 0; j < 8; ++j) { U0r[j] = 0.f; U1r[j] = 0.f; }
    float G0 = NEGF, G1 = NEGF;
    if (g < W) {
      const int hcol = l + g;
      {  // d1: m in [l+2, min(l+g, r-2)]
        int m = l + 2, mend = min(l + g, r - 2);
        if (m <= mend) {
          const float* src;
          size_t base, stride;
          if (k < 16) { src = betau; base = ((size_t)(b * NP + l) * NP) * Tv + k; stride = Tv; }
          else {
            src = betaA;
            base = (size_t)(b * NP) * NP * 384 + (size_t)r * 384 + (size_t)(k - 16) * 24 + hcol;
            stride = (size_t)NP * 384;
          }
          float a_next = src[base + (size_t)m * stride];
          for (; m <= mend; ++m) {
            float a = a_next;
            if (m < mend) a_next = src[base + (size_t)(m + 1) * stride];
            upd(a, k, G1, U1r);
          }
        }
      }
      {  // d0: m in [max(l+g+1, l+2), r-2]
        int m = max(l + g + 1, l + 2), mend = r - 2;
        if (m <= mend) {
          const float* src;
          size_t base, stride;
          if (k < 16) {
            src = betaA;
            base = ((size_t)(b * NP + l) * NP) * 384 + (size_t)k * 24 + hcol;
            stride = 384;
          } else {
            src = betau;
            base = (size_t)(b * NP) * NP * Tv + (size_t)r * Tv + (k - 16);
            stride = (size_t)NP * Tv;
          }
          float a_next = src[base + (size_t)m * stride];
          for (; m <= mend; ++m) {
            float a = a_next;
            if (m < mend) a_next = src[base + (size_t)(m + 1) * stride];
            upd(a, k, G0, U0r);
          }
        }
      }
#pragma unroll
      for (int j = 0; j < 8; ++j) {
        U0[g * 256 + k + 32 * j] = U0r[j];
        U1[g * 256 + k + 32 * j] = U1r[j];
      }
      if (k == 0) { sG0[g] = G0; sG1[g] = G1; }
    }
    __syncthreads();

    // ---- Phase B: per (head,dir) contraction ----
    {
      const int w = tid >> 6, lane = tid & 63;
      const int A = lane >> 2, q = lane & 3;
      for (int p = w; p < 2 * W; p += 12) {
        const int hh = p >> 1, d = p & 1;
        const int h = l + hh;
        const float* Urow = (d ? U1 : U0) + hh * 256 + 4 * q;
        const float* Rb = RNT + (((size_t)(b * 2 + d) * Nv + h) * NTv + A) * 256 + 4 * q;
        float acc = 0.f;
#pragma unroll
        for (int sL = 0; sL < 16; ++sL) {
          float4 u = *(const float4*)(Urow + sL * 16);
          float4 rv = *(const float4*)(Rb + sL * 16);
          acc += u.x * rv.x + u.y * rv.y + u.z * rv.z + u.w * rv.w;
        }
        acc += __shfl_xor(acc, 1, 64);
        acc += __shfl_xor(acc, 2, 64);
        float Mi = d ? sG1[hh] : sG0[hh];
        float sh2 = NEGF, S2 = 0.f, sh3 = NEGF, S3 = 0.f;
        if (W >= 3) {
          if (d == 0) {
            if (hh < W - 1) {
              const float* Tb = T0 + (((size_t)(b * Nv + h) * Nv + (r - 1)) * NTv + 4 * q) * NTv + A;
              edge_dot(cLs[(4 * q + 0) * 25 + hh], cLs[(4 * q + 1) * 25 + hh],
                       cLs[(4 * q + 2) * 25 + hh], cLs[(4 * q + 3) * 25 + hh], Tb, sh2, S2);
            }
            if (hh == 0) {
              const float* Tb = T0L + ((size_t)(b * Nv + l) * NTv + 4 * q) * NTv + A;
              edge_dot(eeRs[4 * q + 0], eeRs[4 * q + 1], eeRs[4 * q + 2], eeRs[4 * q + 3],
                       Tb, sh3, S3);
            }
          } else {
            if (hh >= 1) {
              const float* Tb = T1 + (((size_t)(b * Nv + h) * Nv + l) * NTv + 4 * q) * NTv + A;
              edge_dot(ecRs[(4 * q + 0) * 25 + hh], ecRs[(4 * q + 1) * 25 + hh],
                       ecRs[(4 * q + 2) * 25 + hh], ecRs[(4 * q + 3) * 25 + hh], Tb, sh2, S2);
            }
            if (hh == W - 1) {
              const float* Tb = T1R + ((size_t)(b * Nv + (r - 1)) * NTv + 4 * q) * NTv + A;
              edge_dot(eLs[4 * q + 0], eLs[4 * q + 1], eLs[4 * q + 2], eLs[4 * q + 3],
                       Tb, sh3, S3);
            }
          }
        } else {
          if (d == 0 && hh == 0) { sh2 = 0.f; S2 = D0[((size_t)b * Nv + l) * NTv + A]; }
          if (d == 1 && hh == 1) { sh2 = 0.f; S2 = D1[((size_t)b * Nv + l) * NTv + A]; }
        }
        float Mf = fmaxf(Mi, fmaxf(sh2, sh3));
        float Sf = acc * __expf(Mi - Mf) + S2 * __expf(sh2 - Mf) + S3 * __expf(sh3 - Mf);
        if (q == 0) {
          pM[(d * 24 + hh) * 16 + A] = Mf;
          pS[(d * 24 + hh) * 16 + A] = Sf;
        }
      }
    }
    __syncthreads();
    // combine dirs, write betaA; prep betau input
    if (tid < 384) {
      int A2 = tid & 15, hh = tid >> 4;
      if (hh < W) {
        float M0 = pM[(0 * 24 + hh) * 16 + A2], S0 = pS[(0 * 24 + hh) * 16 + A2];
        float M1 = pM[(1 * 24 + hh) * 16 + A2], S1 = pS[(1 * 24 + hh) * 16 + A2];
        float nm = fmaxf(M0, M1);
        float s = S0 * __expf(M0 - nm) + S1 * __expf(M1 - nm);
        float val = nm + __logf(s);
        betaA[((size_t)(b * NP + l) * NP + r) * 384 + A2 * 24 + (l + hh)] = val;
        sTmp[A2 * 24 + hh] = val + unary[(size_t)(b * Nv + (l + hh)) * Tv + A2];
      }
    }
    __syncthreads();
    if (tid < 16) {
      float mx = NEGF;
      for (int x = 0; x < W; ++x) mx = fmaxf(mx, sTmp[tid * 24 + x]);
      float s = 0.f;
      for (int x = 0; x < W; ++x) s += __expf(sTmp[tid * 24 + x] - mx);
      betau[((size_t)(b * NP + l) * NP + r) * Tv + tid] = mx + __logf(s);
    }
    __syncthreads();  // all span writes drained
    if (tid == 0)
      __hip_atomic_store(&flags[(b * NP + l) * NP + r], 1, __ATOMIC_RELEASE,
                         __HIP_MEMORY_SCOPE_AGENT);
  }
}

// ================= fallback path (small ws): R1-style, known-correct =================
__global__ void init_betau_kernel(const float* __restrict__ unary, float* __restrict__ betau) {
  int t = blockIdx.x * blockDim.x + threadIdx.x;
  if (t >= Bv * Nv * 48) return;
  int i = t % 48, kk = (t / 48) % Nv, b = t / (48 * Nv);
  betau[((size_t)(b * NP + kk) * NP + (kk + 1)) * Tv + 16 + i] =
      unary[(size_t)(b * Nv + kk) * Tv + 16 + i];
}

__global__ __launch_bounds__(768) void width_kernel_fb(
    const float* __restrict__ unary, const float* __restrict__ rule,
    float* __restrict__ betaA, float* __restrict__ betau, int W) {
  const int l = blockIdx.x, b = blockIdx.y;
  const int r = l + W;
  const int tid = threadIdx.x;
  const int sub = tid & 1;
  const int pid = tid >> 1;
  const int A = pid & 15;
  const int hh = pid >> 4;
  const int h = l + hh;
  const bool act = (hh < W);
  const int sA = tid & 15, sH = tid >> 4;

  __shared__ float sER0[48], sEL1[48];
  __shared__ float sCL0[16 * 24], sCR1[16 * 24];
  __shared__ float sMaxL0[24], sMaxR1[24];
  __shared__ float sShR0, sShL1;
  __shared__ float sTmp[16 * 24];

  float runM = NEGF, runS = 0.f;
  for (int m = l + 1; m < r; ++m) {
    const int wl = m - l, wr = r - m;
    if (tid < 64) {
      const int n = (wr == 1) ? 48 : 16, s0 = (wr == 1) ? 16 : 0;
      float v = (tid < n) ? betau[(size_t)((b * NP + m) * NP + r) * Tv + s0 + tid] : NEGF;
      float mx = v;
#pragma unroll
      for (int off = 32; off; off >>= 1) mx = fmaxf(mx, __shfl_xor(mx, off, 64));
      if (tid == 0) sShR0 = mx;
      if (tid < n) sER0[tid] = v - mx;
    } else if (tid < 128) {
      const int j = tid - 64;
      const int n = (wl == 1) ? 48 : 16, s0 = (wl == 1) ? 16 : 0;
      float v = (j < n) ? betau[(size_t)((b * NP + l) * NP + m) * Tv + s0 + j] : NEGF;
      float mx = v;
#pragma unroll
      for (int off = 32; off; off >>= 1) mx = fmaxf(mx, __shfl_xor(mx, off, 64));
      if (j == 0) sShL1 = mx;
      if (j < n) sEL1[j] = v - mx;
    }
    if (tid < 384) {
      if (wl > 1 && sH < wl) {
        float v = betaA[(size_t)((b * NP + l) * NP + m) * 384 + sA * Nv + (l + sH)];
        float mx = v;
#pragma unroll
        for (int off = 8; off; off >>= 1) mx = fmaxf(mx, __shfl_xor(mx, off, 16));
        if (sA == 0) sMaxL0[sH] = mx;
        sCL0[sA * Nv + sH] = v - mx;
      }
      if (wr > 1 && sH >= wl && sH < W) {
        float v = betaA[(size_t)((b * NP + m) * NP + r) * 384 + sA * Nv + (l + sH)];
        float mx = v;
#pragma unroll
        for (int off = 8; off; off >>= 1) mx = fmaxf(mx, __shfl_xor(mx, off, 16));
        if (sA == 0) sMaxR1[sH] = mx;
        sCR1[sA * Nv + sH] = v - mx;
      }
    }
    __syncthreads();
    if (act) {
      if (hh < wl && (wl > 1 || hh == 0)) {
        const int nL = (wl == 1) ? 48 : 16, sL0 = (wl == 1) ? 16 : 0;
        const int nR = (wr == 1) ? 48 : 16, sR0 = (wr == 1) ? 16 : 0;
        const float shift = ((wl == 1) ? 0.f : sMaxL0[hh]) + sShR0;
        float part = 0.f;
        const float* rb = rule + (size_t)(((b * NTv + A) * Nv + h) * Tv) * Tv * 2;
        for (int i = sub; i < nL; i += 2) {
          const float cl = (wl == 1) ? 0.f : sCL0[i * Nv + hh];
          const float* rp = rb + (size_t)(sL0 + i) * Tv * 2 + sR0 * 2;
#pragma unroll 8
          for (int j = 0; j < nR; ++j) part += __expf(cl + sER0[j] + rp[j * 2]);
        }
        float nm = fmaxf(runM, shift);
        runS = runS * __expf(runM - nm) + part * __expf(shift - nm);
        runM = nm;
      }
      if (hh >= wl && (wr > 1 || hh == W - 1)) {
        const int nL = (wl == 1) ? 48 : 16, sL0 = (wl == 1) ? 16 : 0;
        const int nR = (wr == 1) ? 48 : 16, sR0 = (wr == 1) ? 16 : 0;
        const float shift = sShL1 + ((wr == 1) ? 0.f : sMaxR1[hh]);
        float part = 0.f;
        const float* rb = rule + (size_t)(((b * NTv + A) * Nv + h) * Tv) * Tv * 2 + 1;
        for (int i = sub; i < nL; i += 2) {
          const float el = sEL1[i];
          const float* rp = rb + (size_t)(sL0 + i) * Tv * 2 + sR0 * 2;
#pragma unroll 8
          for (int j = 0; j < nR; ++j) {
            const float cr = (wr == 1) ? 0.f : sCR1[j * Nv + hh];
            part += __expf(el + cr + rp[j * 2]);
          }
        }
        float nm = fmaxf(runM, shift);
        runS = runS * __expf(runM - nm) + part * __expf(shift - nm);
        runM = nm;
      }
    }
    __syncthreads();
  }
  if (act) {
    float om = __shfl_xor(runM, 1, 64);
    float os = __shfl_xor(runS, 1, 64);
    float nm = fmaxf(runM, om);
    float s = runS * __expf(runM - nm) + os * __expf(om - nm);
    if (sub == 0) {
      float val = nm + __logf(s);
      betaA[(size_t)((b * NP + l) * NP + r) * 384 + A * Nv + h] = val;
      sTmp[A * Nv + hh] = val + unary[(b * Nv + h) * Tv + A];
    }
  }
  __syncthreads();
  if (tid < 16) {
    float mx = NEGF;
    for (int x = 0; x < W; ++x) mx = fmaxf(mx, sTmp[tid * Nv + x]);
    float s = 0.f;
    for (int x = 0; x < W; ++x) s += __expf(sTmp[tid * Nv + x] - mx);
    betau[(size_t)((b * NP + l) * NP + r) * Tv + tid] = mx + __logf(s);
  }
}

__global__ void final_kernel(const float* __restrict__ betau, const float* __restrict__ root,
                             float* __restrict__ out) {
  int b = threadIdx.x;
  if (b < Bv) {
    float vals[NTv];
    float mx = NEGF;
#pragma unroll
    for (int A = 0; A < NTv; ++A) {
      float v = betau[(size_t)((b * NP + 0) * NP + Nv) * Tv + A] + root[b * NTv + A];
      vals[A] = v;
      mx = fmaxf(mx, v);
    }
    float s = 0.f;
#pragma unroll
    for (int A = 0; A < NTv; ++A) s += __expf(vals[A] - mx);
    out[b] = mx + __logf(s);
  }
}

extern "C" void kernel_launch(void* const* d_in, const int* in_sizes, int n_in,
                              void* d_out, int out_size, void* d_ws, size_t ws_size,
                              hipStream_t stream) {
  (void)in_sizes; (void)n_in; (void)out_size;
  const float* unary = (const float*)d_in[0];
  const float* rule  = (const float*)d_in[1];
  const float* root  = (const float*)d_in[2];
  float* out = (float*)d_out;
  float* ws = (float*)d_ws;
  float* betaA = ws + BETAA_OFF;
  float* betau = ws + BETAU_OFF;
  const bool fast = ws_size >= (size_t)WS_NEED * sizeof(float);

  if (fast) {
    float* RNT = ws + RNT_OFF;
    float* T0  = ws + T0_OFF;
    float* T1  = ws + T1_OFF;
    float* T0L = ws + T0L_OFF;
    float* T1R = ws + T1R_OFF;
    float* D0  = ws + D0_OFF;
    float* D1  = ws + D1_OFF;
    int* sync  = (int*)(ws + SYNC_OFF);
    int* flags = sync;        // 2500 span flags
    int* cnt   = sync + 2500; // 4 per-b prep counters
    hipMemsetAsync((void*)sync, 0, 2504 * sizeof(int), stream);
    fused_kernel<<<GRID, 768, 0, stream>>>(unary, rule, root, out, betaA, betau,
                                           RNT, T0, T1, T0L, T1R, D0, D1, flags, cnt);
  } else {
    init_betau_kernel<<<(Bv * Nv * 48 + 255) / 256, 256, 0, stream>>>(unary, betau);
    for (int W = 2; W <= Nv; ++W) {
      dim3 grid(Nv - W + 1, Bv);
      width_kernel_fb<<<grid, 768, 0, stream>>>(unary, rule, betaA, betau, W);
    }
    final_kernel<<<1, 64, 0, stream>>>(betau, root, out);
  }
}

// Round 5
// 586.516 us; speedup vs baseline: 1.7072x; 1.7072x over previous
//
#include <hip/hip_runtime.h>
#include <cstddef>

#define Bv 4
#define Nv 24
#define NTv 16
#define Tv 64
#define NP 25
#define NEGF (-1e30f)

// ---------------- workspace layout (floats) ----------------
#define BETAA_OFF 0         // [B][25][25][16 sym][24 head]            960000
#define BETAU_OFF 960000    // [B][25][25][64 sym]                     160000
#define RNT_OFF   1120000   // [B][2 d][24 h][16 A][16 sL][16 sR]      786432
#define T0_OFF    1906432   // [B][24 h][24 p][16 sL][16 A]            589824
#define T1_OFF    2496256   // [B][24 h][24 p][16 sR][16 A]            589824
#define T0L_OFF   3086080   // [B][24 h][16 sR][16 A]                  24576
#define T1R_OFF   3110656   // [B][24 h][16 sL][16 A]                  24576
#define D0_OFF    3135232   // [B][24 l][16 A]                         1536
#define D1_OFF    3136768   // [B][24 l][16 A]                         1536
#define EU_OFF    3138304   // [B][24 p][48 j]                         4608
#define MA_OFF    3142912   // [B][25][25][24 h] max_sym betaA         60000
#define MU_OFF    3202912   // [B][25][25]       max_sym betau(NT)     2500
#define WS_NEED   3205412

__device__ __forceinline__ float shflmax16(float v) {
  v = fmaxf(v, __shfl_xor(v, 8, 16));
  v = fmaxf(v, __shfl_xor(v, 4, 16));
  v = fmaxf(v, __shfl_xor(v, 2, 16));
  v = fmaxf(v, __shfl_xor(v, 1, 16));
  return v;
}

// ---- init: width-1 betau + exp(unary) table ----
__global__ void init_kernel(const float* __restrict__ unary, float* __restrict__ betau,
                            float* __restrict__ Eu) {
  int t = blockIdx.x * blockDim.x + threadIdx.x;
  if (t >= Bv * Nv * 48) return;
  int i = t % 48, kk = (t / 48) % Nv, b = t / (48 * Nv);
  float u = unary[(size_t)(b * Nv + kk) * Tv + 16 + i];
  betau[((size_t)(b * NP + kk) * NP + (kk + 1)) * Tv + 16 + i] = u;
  Eu[(size_t)(b * Nv + kk) * 48 + i] = __expf(u);
}

// ---- fused prep: block per (b,A,h); coalesced 32KB rule read; all precontractions ----
__global__ __launch_bounds__(256) void prep_kernel(
    const float* __restrict__ rule, const float* __restrict__ Eu,
    float* __restrict__ RNT, float* __restrict__ T0, float* __restrict__ T1,
    float* __restrict__ T0L, float* __restrict__ T1R,
    float* __restrict__ D0, float* __restrict__ D1) {
  const int h = blockIdx.x, A = blockIdx.y, b = blockIdx.z;
  const int t = threadIdx.x;  // 256
  __shared__ float er0[64 * 65];
  __shared__ float er1[64 * 65];
  __shared__ float E[24 * 48];
  __shared__ float red[256];

  for (int i = t; i < 24 * 48; i += 256) E[i] = Eu[(size_t)b * (24 * 48) + i];
  const float* rb = rule + (size_t)((b * NTv + A) * Nv + h) * 8192;
#pragma unroll
  for (int i = 0; i < 8; ++i) {
    int lin = i * 1024 + t * 4;  // sL*128 + sR*2 + d
    float4 v = *(const float4*)(rb + lin);
    int sL = lin >> 7, rem = (lin & 127) >> 1;
    er0[sL * 65 + rem] = __expf(v.x);
    er1[sL * 65 + rem] = __expf(v.y);
    er0[sL * 65 + rem + 1] = __expf(v.z);
    er1[sL * 65 + rem + 1] = __expf(v.w);
  }
  __syncthreads();
  {  // RNT, A-major
    float* dst0 = RNT + (((size_t)(b * 2 + 0) * Nv + h) * NTv + A) * 256;
    float* dst1 = RNT + (((size_t)(b * 2 + 1) * Nv + h) * NTv + A) * 256;
    dst0[t] = er0[(t >> 4) * 65 + (t & 15)];
    dst1[t] = er1[(t >> 4) * 65 + (t & 15)];
  }
  for (int o = t; o < 384; o += 256) {  // T0 / T1
    int p = o >> 4, sL = o & 15;
    const float* Ep = E + p * 48;
    const float* r0 = er0 + sL * 65 + 16;
    float a0 = 0.f, a1 = 0.f;
#pragma unroll 8
    for (int j = 0; j < 48; ++j) a0 += Ep[j] * r0[j];
#pragma unroll 8
    for (int i = 0; i < 48; ++i) a1 += Ep[i] * er1[(16 + i) * 65 + sL];
    T0[(((size_t)(b * Nv + h) * Nv + p) * NTv + sL) * NTv + A] = a0;
    T1[(((size_t)(b * Nv + h) * Nv + p) * NTv + sL) * NTv + A] = a1;
  }
  if (t < 16) {  // T0L
    float acc = 0.f;
    for (int i = 0; i < 48; ++i) acc += er0[(16 + i) * 65 + t];
    T0L[((size_t)(b * Nv + h) * NTv + t) * NTv + A] = acc;
  } else if (t < 32) {  // T1R
    int sL = t - 16;
    float acc = 0.f;
    for (int j = 0; j < 48; ++j) acc += er1[sL * 65 + 16 + j];
    T1R[((size_t)(b * Nv + h) * NTv + sL) * NTv + A] = acc;
  }
  // D0 / D1
  float acc0 = 0.f, acc1 = 0.f;
  const int hp = (h + 1 < 24) ? h + 1 : 0, hm = (h >= 1) ? h - 1 : 0;
  for (int e = t; e < 2304; e += 256) {
    int i = e / 48, j = e % 48;
    acc0 += E[hp * 48 + j] * er0[(16 + i) * 65 + 16 + j];
    acc1 += E[hm * 48 + i] * er1[(16 + i) * 65 + 16 + j];
  }
  red[t] = acc0;
  __syncthreads();
  if (t < 64) {
    float s = red[t] + red[t + 64] + red[t + 128] + red[t + 192];
#pragma unroll
    for (int off = 32; off; off >>= 1) s += __shfl_xor(s, off, 64);
    if (t == 0 && h <= 22) D0[((size_t)b * Nv + h) * NTv + A] = s;
  }
  __syncthreads();
  red[t] = acc1;
  __syncthreads();
  if (t < 64) {
    float s = red[t] + red[t + 64] + red[t + 128] + red[t + 192];
#pragma unroll
    for (int off = 32; off; off >>= 1) s += __shfl_xor(s, off, 64);
    if (t == 0 && h >= 1) D1[((size_t)b * Nv + (h - 1)) * NTv + A] = s;
  }
}

__device__ __forceinline__ void edge_dot(float v0, float v1, float v2, float v3,
                                         const float* Tb, float& sh, float& S) {
  float mx = fmaxf(fmaxf(v0, v1), fmaxf(v2, v3));
  mx = fmaxf(mx, __shfl_xor(mx, 1, 64));
  mx = fmaxf(mx, __shfl_xor(mx, 2, 64));
  float dot = __expf(v0 - mx) * Tb[0] + __expf(v1 - mx) * Tb[16] +
              __expf(v2 - mx) * Tb[32] + __expf(v3 - mx) * Tb[48];
  dot += __shfl_xor(dot, 1, 64);
  dot += __shfl_xor(dot, 2, 64);
  sh = mx;
  S = dot;
}

// ---- width kernel: fixed-shift Phase A (independent split iterations) ----
__global__ __launch_bounds__(768) void width_kernel4(
    const float* __restrict__ unary, float* __restrict__ betaA, float* __restrict__ betau,
    const float* __restrict__ RNT, const float* __restrict__ T0, const float* __restrict__ T1,
    const float* __restrict__ T0L, const float* __restrict__ T1R,
    const float* __restrict__ D0, const float* __restrict__ D1,
    float* __restrict__ MA, float* __restrict__ MU, int W) {
  const int l = blockIdx.x, b = blockIdx.y;
  const int r = l + W;
  const int tid = threadIdx.x;

  __shared__ float U0[24 * 256], U1[24 * 256];
  __shared__ float sG0[24], sG1[24];
  __shared__ float cLs[16 * 25], ecRs[16 * 25];
  __shared__ float eLs[16], eeRs[16];
  __shared__ float pM[2 * 24 * 16], pS[2 * 24 * 16];
  __shared__ float sTmp[16 * 24];

  // ---- edge staging (no barrier needed until Phase B) ----
  if (W >= 3) {
    if (tid < 384) {
      int s = tid / 24, j = tid % 24, jj = j - l;
      float v = betaA[((size_t)(b * NP + l) * NP + (r - 1)) * 384 + s * 24 + j];
      if (jj >= 0 && jj < 24) cLs[s * 25 + jj] = v;
    } else {
      int t2 = tid - 384;
      int s = t2 / 24, j = t2 % 24, jj = j - l;
      float v = betaA[((size_t)(b * NP + (l + 1)) * NP + r) * 384 + s * 24 + j];
      if (jj >= 0 && jj < 24) ecRs[s * 25 + jj] = v;
    }
    if (tid < 16) eLs[tid] = betau[((size_t)(b * NP + l) * NP + (r - 1)) * Tv + tid];
    else if (tid >= 32 && tid < 48)
      eeRs[tid - 32] = betau[((size_t)(b * NP + (l + 1)) * NP + r) * Tv + (tid - 32)];
  }

  // ---- Phase A ----
  const int g = tid >> 5, k = tid & 31;
  const int cnt = W - 3;  // interior splits m = l+2 .. r-2
  float U0r[8], U1r[8];
#pragma unroll
  for (int j = 0; j < 8; ++j) { U0r[j] = 0.f; U1r[j] = 0.f; }
  float G0 = NEGF, G1 = NEGF;

  if (g < W) {
    const int h = l + g;
    // pre-pass: lane i owns split m = l+2+i
    float pMAlm = NEGF, pMUlm = NEGF, pMAmr = NEGF, pMUmr = NEGF;
    float sh0 = NEGF, sh1 = NEGF;
    if (k < cnt) {
      int m = l + 2 + k;
      pMAlm = MA[((size_t)(b * NP + l) * NP + m) * 24 + h];
      pMUlm = MU[(size_t)(b * NP + l) * NP + m];
      pMAmr = MA[((size_t)(b * NP + m) * NP + r) * 24 + h];
      pMUmr = MU[(size_t)(b * NP + m) * NP + r];
      if (k >= g - 1) sh0 = pMAlm + pMUmr;  // head in left child (m >= l+g+1)
      if (k <= g - 2) sh1 = pMUlm + pMAmr;  // head in right child (m <= l+g)
    }
    float m0 = sh0, m1 = sh1;
#pragma unroll
    for (int off = 16; off; off >>= 1) {
      m0 = fmaxf(m0, __shfl_xor(m0, off, 32));
      m1 = fmaxf(m1, __shfl_xor(m1, off, 32));
    }
    G0 = m0;
    G1 = m1;
    float pw0 = (sh0 == NEGF) ? 0.f : __expf(sh0 - G0);
    float pw1 = (sh1 == NEGF) ? 0.f : __expf(sh1 - G1);

    if (cnt > 0) {
      size_t cbase, cstr, bbase, bstr;
      if (k < 16) {
        cbase = ((size_t)(b * NP + l) * NP) * 384 + (size_t)k * 24 + h;  // betaA[b,l,m]
        cstr = 384;
        bbase = ((size_t)(b * NP + l) * NP) * 64 + k;                    // betau[b,l,m]
        bstr = 64;
      } else {
        cbase = (size_t)(b * NP) * NP * 384 + (size_t)r * 384 + (size_t)(k - 16) * 24 + h;
        cstr = (size_t)NP * 384;                                         // betaA[b,m,r]
        bbase = (size_t)(b * NP) * NP * 64 + (size_t)r * 64 + (k - 16);  // betau[b,m,r]
        bstr = (size_t)NP * 64;
      }
      const int mlo = l + 2;
      float cv = betaA[cbase + (size_t)mlo * cstr];
      float bv = betau[bbase + (size_t)mlo * bstr];
      for (int i = 0; i < cnt; ++i) {
        float cvn = 0.f, bvn = 0.f;
        if (i + 1 < cnt) {
          cvn = betaA[cbase + (size_t)(mlo + i + 1) * cstr];
          bvn = betau[bbase + (size_t)(mlo + i + 1) * bstr];
        }
        float bMAlm = __shfl(pMAlm, i, 32), bMUlm = __shfl(pMUlm, i, 32);
        float bMAmr = __shfl(pMAmr, i, 32), bMUmr = __shfl(pMUmr, i, 32);
        float bw0 = __shfl(pw0, i, 32), bw1 = __shfl(pw1, i, 32);
        float subc = (k < 16) ? bMAlm : bMAmr;
        float subb = (k < 16) ? bMUlm : bMUmr;
        // clamp: out-of-range chart reads are garbage; min(.,0) keeps them finite,
        // and the corresponding w is 0 so they contribute nothing.
        float eC = __expf(fminf(cv - subc, 0.f));
        float eB = __expf(fminf(bv - subb, 0.f));
        float s0 = __shfl(eB, 16 + (k & 15), 32) * bw0;  // dir0: betauR side
        float s1 = __shfl(eC, 16 + (k & 15), 32) * bw1;  // dir1: chartR side
#pragma unroll
        for (int j = 0; j < 8; ++j) {
          int sL = (k >> 4) + 2 * j;
          U0r[j] = fmaf(__shfl(eC, sL, 32), s0, U0r[j]);  // chartL x betauR
          U1r[j] = fmaf(__shfl(eB, sL, 32), s1, U1r[j]);  // betauL x chartR
        }
        cv = cvn;
        bv = bvn;
      }
    }
#pragma unroll
    for (int j = 0; j < 8; ++j) {
      U0[g * 256 + k + 32 * j] = U0r[j];
      U1[g * 256 + k + 32 * j] = U1r[j];
    }
    if (k == 0) { sG0[g] = G0; sG1[g] = G1; }
  }
  __syncthreads();

  // ---- Phase B: per (head,dir) contraction ----
  {
    const int w = tid >> 6, lane = tid & 63;
    const int A = lane >> 2, q = lane & 3;
    for (int p = w; p < 2 * W; p += 12) {
      const int hh = p >> 1, d = p & 1;
      const int h = l + hh;
      const float* Urow = (d ? U1 : U0) + hh * 256 + 4 * q;
      const float* Rb = RNT + (((size_t)(b * 2 + d) * Nv + h) * NTv + A) * 256 + 4 * q;
      float acc = 0.f;
#pragma unroll
      for (int sL = 0; sL < 16; ++sL) {
        float4 u = *(const float4*)(Urow + sL * 16);
        float4 rv = *(const float4*)(Rb + sL * 16);
        acc += u.x * rv.x + u.y * rv.y + u.z * rv.z + u.w * rv.w;
      }
      acc += __shfl_xor(acc, 1, 64);
      acc += __shfl_xor(acc, 2, 64);
      float Mi = d ? sG1[hh] : sG0[hh];
      float sh2 = NEGF, S2 = 0.f, sh3 = NEGF, S3 = 0.f;
      if (W >= 3) {
        if (d == 0) {
          if (hh < W - 1) {
            const float* Tb = T0 + (((size_t)(b * Nv + h) * Nv + (r - 1)) * NTv + 4 * q) * NTv + A;
            edge_dot(cLs[(4 * q + 0) * 25 + hh], cLs[(4 * q + 1) * 25 + hh],
                     cLs[(4 * q + 2) * 25 + hh], cLs[(4 * q + 3) * 25 + hh], Tb, sh2, S2);
          }
          if (hh == 0) {
            const float* Tb = T0L + ((size_t)(b * Nv + l) * NTv + 4 * q) * NTv + A;
            edge_dot(eeRs[4 * q + 0], eeRs[4 * q + 1], eeRs[4 * q + 2], eeRs[4 * q + 3],
                     Tb, sh3, S3);
          }
        } else {
          if (hh >= 1) {
            const float* Tb = T1 + (((size_t)(b * Nv + h) * Nv + l) * NTv + 4 * q) * NTv + A;
            edge_dot(ecRs[(4 * q + 0) * 25 + hh], ecRs[(4 * q + 1) * 25 + hh],
                     ecRs[(4 * q + 2) * 25 + hh], ecRs[(4 * q + 3) * 25 + hh], Tb, sh2, S2);
          }
          if (hh == W - 1) {
            const float* Tb = T1R + ((size_t)(b * Nv + (r - 1)) * NTv + 4 * q) * NTv + A;
            edge_dot(eLs[4 * q + 0], eLs[4 * q + 1], eLs[4 * q + 2], eLs[4 * q + 3],
                     Tb, sh3, S3);
          }
        }
      } else {
        if (d == 0 && hh == 0) { sh2 = 0.f; S2 = D0[((size_t)b * Nv + l) * NTv + A]; }
        if (d == 1 && hh == 1) { sh2 = 0.f; S2 = D1[((size_t)b * Nv + l) * NTv + A]; }
      }
      float Mf = fmaxf(Mi, fmaxf(sh2, sh3));
      float Sf = acc * __expf(Mi - Mf) + S2 * __expf(sh2 - Mf) + S3 * __expf(sh3 - Mf);
      if (q == 0) {
        pM[(d * 24 + hh) * 16 + A] = Mf;
        pS[(d * 24 + hh) * 16 + A] = Sf;
      }
    }
  }
  __syncthreads();
  // combine dirs, write betaA + MA; prep betau input
  if (tid < 384) {
    int A2 = tid & 15, hh = tid >> 4;
    if (hh < W) {
      float M0 = pM[(0 * 24 + hh) * 16 + A2], S0 = pS[(0 * 24 + hh) * 16 + A2];
      float M1 = pM[(1 * 24 + hh) * 16 + A2], S1 = pS[(1 * 24 + hh) * 16 + A2];
      float nm = fmaxf(M0, M1);
      float s = S0 * __expf(M0 - nm) + S1 * __expf(M1 - nm);
      float val = nm + __logf(s);
      betaA[((size_t)(b * NP + l) * NP + r) * 384 + A2 * 24 + (l + hh)] = val;
      sTmp[A2 * 24 + hh] = val + unary[(size_t)(b * Nv + (l + hh)) * Tv + A2];
      float mv = shflmax16(val);
      if (A2 == 0) MA[((size_t)(b * NP + l) * NP + r) * 24 + (l + hh)] = mv;
    }
  }
  __syncthreads();
  if (tid < 16) {
    float mx = NEGF;
    for (int x = 0; x < W; ++x) mx = fmaxf(mx, sTmp[tid * 24 + x]);
    float s = 0.f;
    for (int x = 0; x < W; ++x) s += __expf(sTmp[tid * 24 + x] - mx);
    float v = mx + __logf(s);
    betau[((size_t)(b * NP + l) * NP + r) * Tv + tid] = v;
    float mv = shflmax16(v);
    if (tid == 0) MU[(size_t)(b * NP + l) * NP + r] = mv;
  }
}

// ================= fallback path (small ws): R1-style, known-correct =================
__global__ void init_betau_kernel(const float* __restrict__ unary, float* __restrict__ betau) {
  int t = blockIdx.x * blockDim.x + threadIdx.x;
  if (t >= Bv * Nv * 48) return;
  int i = t % 48, kk = (t / 48) % Nv, b = t / (48 * Nv);
  betau[((size_t)(b * NP + kk) * NP + (kk + 1)) * Tv + 16 + i] =
      unary[(size_t)(b * Nv + kk) * Tv + 16 + i];
}

__global__ __launch_bounds__(768) void width_kernel_fb(
    const float* __restrict__ unary, const float* __restrict__ rule,
    float* __restrict__ betaA, float* __restrict__ betau, int W) {
  const int l = blockIdx.x, b = blockIdx.y;
  const int r = l + W;
  const int tid = threadIdx.x;
  const int sub = tid & 1;
  const int pid = tid >> 1;
  const int A = pid & 15;
  const int hh = pid >> 4;
  const int h = l + hh;
  const bool act = (hh < W);
  const int sA = tid & 15, sH = tid >> 4;

  __shared__ float sER0[48], sEL1[48];
  __shared__ float sCL0[16 * 24], sCR1[16 * 24];
  __shared__ float sMaxL0[24], sMaxR1[24];
  __shared__ float sShR0, sShL1;
  __shared__ float sTmp[16 * 24];

  float runM = NEGF, runS = 0.f;
  for (int m = l + 1; m < r; ++m) {
    const int wl = m - l, wr = r - m;
    if (tid < 64) {
      const int n = (wr == 1) ? 48 : 16, s0 = (wr == 1) ? 16 : 0;
      float v = (tid < n) ? betau[(size_t)((b * NP + m) * NP + r) * Tv + s0 + tid] : NEGF;
      float mx = v;
#pragma unroll
      for (int off = 32; off; off >>= 1) mx = fmaxf(mx, __shfl_xor(mx, off, 64));
      if (tid == 0) sShR0 = mx;
      if (tid < n) sER0[tid] = v - mx;
    } else if (tid < 128) {
      const int j = tid - 64;
      const int n = (wl == 1) ? 48 : 16, s0 = (wl == 1) ? 16 : 0;
      float v = (j < n) ? betau[(size_t)((b * NP + l) * NP + m) * Tv + s0 + j] : NEGF;
      float mx = v;
#pragma unroll
      for (int off = 32; off; off >>= 1) mx = fmaxf(mx, __shfl_xor(mx, off, 64));
      if (j == 0) sShL1 = mx;
      if (j < n) sEL1[j] = v - mx;
    }
    if (tid < 384) {
      if (wl > 1 && sH < wl) {
        float v = betaA[(size_t)((b * NP + l) * NP + m) * 384 + sA * Nv + (l + sH)];
        float mx = v;
#pragma unroll
        for (int off = 8; off; off >>= 1) mx = fmaxf(mx, __shfl_xor(mx, off, 16));
        if (sA == 0) sMaxL0[sH] = mx;
        sCL0[sA * Nv + sH] = v - mx;
      }
      if (wr > 1 && sH >= wl && sH < W) {
        float v = betaA[(size_t)((b * NP + m) * NP + r) * 384 + sA * Nv + (l + sH)];
        float mx = v;
#pragma unroll
        for (int off = 8; off; off >>= 1) mx = fmaxf(mx, __shfl_xor(mx, off, 16));
        if (sA == 0) sMaxR1[sH] = mx;
        sCR1[sA * Nv + sH] = v - mx;
      }
    }
    __syncthreads();
    if (act) {
      if (hh < wl && (wl > 1 || hh == 0)) {
        const int nL = (wl == 1) ? 48 : 16, sL0 = (wl == 1) ? 16 : 0;
        const int nR = (wr == 1) ? 48 : 16, sR0 = (wr == 1) ? 16 : 0;
        const float shift = ((wl == 1) ? 0.f : sMaxL0[hh]) + sShR0;
        float part = 0.f;
        const float* rb = rule + (size_t)(((b * NTv + A) * Nv + h) * Tv) * Tv * 2;
        for (int i = sub; i < nL; i += 2) {
          const float cl = (wl == 1) ? 0.f : sCL0[i * Nv + hh];
          const float* rp = rb + (size_t)(sL0 + i) * Tv * 2 + sR0 * 2;
#pragma unroll 8
          for (int j = 0; j < nR; ++j) part += __expf(cl + sER0[j] + rp[j * 2]);
        }
        float nm = fmaxf(runM, shift);
        runS = runS * __expf(runM - nm) + part * __expf(shift - nm);
        runM = nm;
      }
      if (hh >= wl && (wr > 1 || hh == W - 1)) {
        const int nL = (wl == 1) ? 48 : 16, sL0 = (wl == 1) ? 16 : 0;
        const int nR = (wr == 1) ? 48 : 16, sR0 = (wr == 1) ? 16 : 0;
        const float shift = sShL1 + ((wr == 1) ? 0.f : sMaxR1[hh]);
        float part = 0.f;
        const float* rb = rule + (size_t)(((b * NTv + A) * Nv + h) * Tv) * Tv * 2 + 1;
        for (int i = sub; i < nL; i += 2) {
          const float el = sEL1[i];
          const float* rp = rb + (size_t)(sL0 + i) * Tv * 2 + sR0 * 2;
#pragma unroll 8
          for (int j = 0; j < nR; ++j) {
            const float cr = (wr == 1) ? 0.f : sCR1[j * Nv + hh];
            part += __expf(el + cr + rp[j * 2]);
          }
        }
        float nm = fmaxf(runM, shift);
        runS = runS * __expf(runM - nm) + part * __expf(shift - nm);
        runM = nm;
      }
    }
    __syncthreads();
  }
  if (act) {
    float om = __shfl_xor(runM, 1, 64);
    float os = __shfl_xor(runS, 1, 64);
    float nm = fmaxf(runM, om);
    float s = runS * __expf(runM - nm) + os * __expf(om - nm);
    if (sub == 0) {
      float val = nm + __logf(s);
      betaA[(size_t)((b * NP + l) * NP + r) * 384 + A * Nv + h] = val;
      sTmp[A * Nv + hh] = val + unary[(b * Nv + h) * Tv + A];
    }
  }
  __syncthreads();
  if (tid < 16) {
    float mx = NEGF;
    for (int x = 0; x < W; ++x) mx = fmaxf(mx, sTmp[tid * Nv + x]);
    float s = 0.f;
    for (int x = 0; x < W; ++x) s += __expf(sTmp[tid * Nv + x] - mx);
    betau[(size_t)((b * NP + l) * NP + r) * Tv + tid] = mx + __logf(s);
  }
}

__global__ void final_kernel(const float* __restrict__ betau, const float* __restrict__ root,
                             float* __restrict__ out) {
  int b = threadIdx.x;
  if (b < Bv) {
    float vals[NTv];
    float mx = NEGF;
#pragma unroll
    for (int A = 0; A < NTv; ++A) {
      float v = betau[(size_t)((b * NP + 0) * NP + Nv) * Tv + A] + root[b * NTv + A];
      vals[A] = v;
      mx = fmaxf(mx, v);
    }
    float s = 0.f;
#pragma unroll
    for (int A = 0; A < NTv; ++A) s += __expf(vals[A] - mx);
    out[b] = mx + __logf(s);
  }
}

extern "C" void kernel_launch(void* const* d_in, const int* in_sizes, int n_in,
                              void* d_out, int out_size, void* d_ws, size_t ws_size,
                              hipStream_t stream) {
  (void)in_sizes; (void)n_in; (void)out_size;
  const float* unary = (const float*)d_in[0];
  const float* rule  = (const float*)d_in[1];
  const float* root  = (const float*)d_in[2];
  float* out = (float*)d_out;
  float* ws = (float*)d_ws;
  float* betaA = ws + BETAA_OFF;
  float* betau = ws + BETAU_OFF;
  const bool fast = ws_size >= (size_t)WS_NEED * sizeof(float);

  if (fast) {
    float* RNT = ws + RNT_OFF;
    float* T0  = ws + T0_OFF;
    float* T1  = ws + T1_OFF;
    float* T0L = ws + T0L_OFF;
    float* T1R = ws + T1R_OFF;
    float* D0  = ws + D0_OFF;
    float* D1  = ws + D1_OFF;
    float* Eu  = ws + EU_OFF;
    float* MAp = ws + MA_OFF;
    float* MUp = ws + MU_OFF;
    init_kernel<<<(Bv * Nv * 48 + 255) / 256, 256, 0, stream>>>(unary, betau, Eu);
    prep_kernel<<<dim3(24, 16, 4), 256, 0, stream>>>(rule, Eu, RNT, T0, T1, T0L, T1R, D0, D1);
    for (int W = 2; W <= Nv; ++W) {
      dim3 grid(Nv - W + 1, Bv);
      width_kernel4<<<grid, 768, 0, stream>>>(unary, betaA, betau, RNT, T0, T1, T0L, T1R,
                                              D0, D1, MAp, MUp, W);
    }
  } else {
    init_betau_kernel<<<(Bv * Nv * 48 + 255) / 256, 256, 0, stream>>>(unary, betau);
    for (int W = 2; W <= Nv; ++W) {
      dim3 grid(Nv - W + 1, Bv);
      width_kernel_fb<<<grid, 768, 0, stream>>>(unary, rule, betaA, betau, W);
    }
  }
  final_kernel<<<1, 64, 0, stream>>>(betau, root, out);
}